// Round 1
// baseline (249.367 us; speedup 1.0000x reference)
//
#include <hip/hip_runtime.h>
#include <math.h>

#define V_    32000
#define SEQ_  128
#define B_    32
#define E_    32
#define H_    8

// ws layout (float offsets)
#define OFF_XWF  0        // [b][j][t]  32*8*128
#define OFF_XWB  32768
#define OFF_HTF  65536    // [t][b][j]  128*32*8
#define OFF_HTB  98304
#define OFF_PART 131072   // [s][b][chunk4] 4096*4

// ---------------- k1: X = lookup[idx];  xw = X@Wx + bias_x + bias_h ----------------
__global__ __launch_bounds__(256) void k1_embed_xw(
    const int* __restrict__ idx, const float* __restrict__ lookup,
    const float* __restrict__ wxf, const float* __restrict__ wxb,
    const float* __restrict__ bx, const float* __restrict__ bhf,
    const float* __restrict__ bhb, float* __restrict__ ws)
{
    int g = blockIdx.x * 256 + threadIdx.x;   // 0..4095
    int b = g >> 7, t = g & 127;
    int id = idx[t * B_ + b];
    const float* xr = lookup + (long)id * E_;
    float x[E_];
#pragma unroll
    for (int e = 0; e < E_; e += 4) {
        float4 v4 = *(const float4*)(xr + e);
        x[e] = v4.x; x[e+1] = v4.y; x[e+2] = v4.z; x[e+3] = v4.w;
    }
    float* xwf = ws + OFF_XWF;
    float* xwb = ws + OFF_XWB;
#pragma unroll
    for (int j = 0; j < H_; ++j) {
        float af = bx[j] + bhf[j];
        float ab = bx[j] + bhb[j];
#pragma unroll
        for (int e = 0; e < E_; ++e) {
            af += x[e] * wxf[e * H_ + j];
            ab += x[e] * wxb[e * H_ + j];
        }
        xwf[(b * H_ + j) * SEQ_ + t] = af;
        xwb[(b * H_ + j) * SEQ_ + t] = ab;
    }
}

// ---------------- k2: sequential scans (fwd + bwd), shuffle recurrence ----------------
__global__ __launch_bounds__(64) void k2_scan(
    const float* __restrict__ whf, const float* __restrict__ whb,
    const float* __restrict__ hf0, const float* __restrict__ hb0,
    float* __restrict__ ws)
{
    int bid = blockIdx.x;            // 0..7 : 0-3 fwd, 4-7 bwd
    bool bwd = bid >= 4;
    int bbase = (bid & 3) * 8;
    int tid = threadIdx.x;           // 0..63
    int bg = tid >> 3, j = tid & 7;
    int b = bbase + bg;
    const float* wh = bwd ? whb : whf;
    float w[H_];
#pragma unroll
    for (int k = 0; k < H_; ++k) w[k] = wh[k * H_ + j];
    float h = bwd ? hb0[j] : hf0[j];
    const float* xw = ws + (bwd ? OFF_XWB : OFF_XWF) + (b * H_ + j) * SEQ_;
    float* ht = ws + (bwd ? OFF_HTB : OFF_HTF);
    int lanebase = tid & ~7;

    float4 n0, n1;
    {
        int toff = bwd ? 120 : 0;
        n0 = *(const float4*)(xw + toff);
        n1 = *(const float4*)(xw + toff + 4);
    }
    for (int cc = 0; cc < 16; ++cc) {
        float xv[8];
        xv[0]=n0.x; xv[1]=n0.y; xv[2]=n0.z; xv[3]=n0.w;
        xv[4]=n1.x; xv[5]=n1.y; xv[6]=n1.z; xv[7]=n1.w;
        if (cc < 15) {   // prefetch next chunk (independent of h-chain)
            int toff = bwd ? (112 - cc * 8) : ((cc + 1) * 8);
            n0 = *(const float4*)(xw + toff);
            n1 = *(const float4*)(xw + toff + 4);
        }
#pragma unroll
        for (int u = 0; u < 8; ++u) {
            int t = bwd ? (127 - cc * 8 - u) : (cc * 8 + u);
            float xc = bwd ? xv[7 - u] : xv[u];
            ht[t * (B_ * H_) + b * H_ + j] = h;   // write PREVIOUS state (scan semantics)
            float a = xc;
#pragma unroll
            for (int k = 0; k < H_; ++k) {
                float hk = __shfl(h, lanebase + k, 64);
                a += hk * w[k];
            }
            float e2 = __expf(2.0f * a);
            h = 1.0f - 2.0f * __builtin_amdgcn_rcpf(e2 + 1.0f);  // tanh(a)
        }
    }
}

// ---------------- k3: per-row sum of exp(logit) over a V-chunk ----------------
__global__ __launch_bounds__(256, 1) void k3_sumexp(
    const float* __restrict__ wo, const float* __restrict__ bo,
    float* __restrict__ ws)
{
    int s = blockIdx.x >> 2, c = blockIdx.x & 3;
    int vl = threadIdx.x & 63, rg = threadIdx.x >> 6;
    const float* htf = ws + OFF_HTF + s * (B_ * H_);
    const float* htb = ws + OFF_HTB + s * (B_ * H_);
    float h[8][16];
#pragma unroll
    for (int r = 0; r < 8; ++r) {
        int b = rg * 8 + r;
        float4 f0 = *(const float4*)(htf + b * H_);
        float4 f1 = *(const float4*)(htf + b * H_ + 4);
        float4 g0 = *(const float4*)(htb + b * H_);
        float4 g1 = *(const float4*)(htb + b * H_ + 4);
        h[r][0]=f0.x; h[r][1]=f0.y; h[r][2]=f0.z;  h[r][3]=f0.w;
        h[r][4]=f1.x; h[r][5]=f1.y; h[r][6]=f1.z;  h[r][7]=f1.w;
        h[r][8]=g0.x; h[r][9]=g0.y; h[r][10]=g0.z; h[r][11]=g0.w;
        h[r][12]=g1.x; h[r][13]=g1.y; h[r][14]=g1.z; h[r][15]=g1.w;
    }
    float sums[8];
#pragma unroll
    for (int r = 0; r < 8; ++r) sums[r] = 0.0f;
    int v0 = c * 8000;
    for (int i = 0; i < 32; ++i) {
        int v = v0 + i * 256 + vl * 4;
        if (v < v0 + 8000) {
            float4 wv[16];
#pragma unroll
            for (int k = 0; k < 16; ++k) wv[k] = *(const float4*)(wo + k * V_ + v);
            float4 bo4 = *(const float4*)(bo + v);
#pragma unroll
            for (int r = 0; r < 8; ++r) {
                float lx = bo4.x, ly = bo4.y, lz = bo4.z, lw = bo4.w;
#pragma unroll
                for (int k = 0; k < 16; ++k) {
                    lx += h[r][k] * wv[k].x; ly += h[r][k] * wv[k].y;
                    lz += h[r][k] * wv[k].z; lw += h[r][k] * wv[k].w;
                }
                sums[r] += ((__expf(lx) + __expf(ly)) + (__expf(lz) + __expf(lw)));
            }
        }
    }
#pragma unroll
    for (int r = 0; r < 8; ++r) {
        float sv = sums[r];
#pragma unroll
        for (int m = 32; m > 0; m >>= 1) sv += __shfl_xor(sv, m, 64);
        sums[r] = sv;
    }
    if (vl == 0) {
#pragma unroll
        for (int r = 0; r < 8; ++r) {
            int b = rg * 8 + r;
            ws[OFF_PART + (s * B_ + b) * 4 + c] = sums[r];
        }
    }
}

// ---------------- k4: recompute logits, write logit - LSE ----------------
__global__ __launch_bounds__(256, 1) void k4_write(
    const float* __restrict__ wo, const float* __restrict__ bo,
    const float* __restrict__ ws, float* __restrict__ out)
{
    __shared__ float lseS[B_];
    int s = blockIdx.x >> 2, c = blockIdx.x & 3;
    int tid = threadIdx.x;
    if (tid < B_) {
        const float* p = ws + OFF_PART + (s * B_ + tid) * 4;
        lseS[tid] = logf(((p[0] + p[1]) + (p[2] + p[3])));
    }
    __syncthreads();
    int vl = tid & 63, rg = tid >> 6;
    const float* htf = ws + OFF_HTF + s * (B_ * H_);
    const float* htb = ws + OFF_HTB + s * (B_ * H_);
    float h[8][16];
    float lse[8];
#pragma unroll
    for (int r = 0; r < 8; ++r) {
        int b = rg * 8 + r;
        float4 f0 = *(const float4*)(htf + b * H_);
        float4 f1 = *(const float4*)(htf + b * H_ + 4);
        float4 g0 = *(const float4*)(htb + b * H_);
        float4 g1 = *(const float4*)(htb + b * H_ + 4);
        h[r][0]=f0.x; h[r][1]=f0.y; h[r][2]=f0.z;  h[r][3]=f0.w;
        h[r][4]=f1.x; h[r][5]=f1.y; h[r][6]=f1.z;  h[r][7]=f1.w;
        h[r][8]=g0.x; h[r][9]=g0.y; h[r][10]=g0.z; h[r][11]=g0.w;
        h[r][12]=g1.x; h[r][13]=g1.y; h[r][14]=g1.z; h[r][15]=g1.w;
        lse[r] = lseS[b];
    }
    int v0 = c * 8000;
    for (int i = 0; i < 32; ++i) {
        int v = v0 + i * 256 + vl * 4;
        if (v < v0 + 8000) {
            float4 wv[16];
#pragma unroll
            for (int k = 0; k < 16; ++k) wv[k] = *(const float4*)(wo + k * V_ + v);
            float4 bo4 = *(const float4*)(bo + v);
#pragma unroll
            for (int r = 0; r < 8; ++r) {
                float lx = bo4.x, ly = bo4.y, lz = bo4.z, lw = bo4.w;
#pragma unroll
                for (int k = 0; k < 16; ++k) {
                    lx += h[r][k] * wv[k].x; ly += h[r][k] * wv[k].y;
                    lz += h[r][k] * wv[k].z; lw += h[r][k] * wv[k].w;
                }
                float4 o;
                o.x = lx - lse[r]; o.y = ly - lse[r];
                o.z = lz - lse[r]; o.w = lw - lse[r];
                long row = (long)(s * B_ + rg * 8 + r);
                *(float4*)(out + row * V_ + v) = o;
            }
        }
    }
}

extern "C" void kernel_launch(void* const* d_in, const int* in_sizes, int n_in,
                              void* d_out, int out_size, void* d_ws, size_t ws_size,
                              hipStream_t stream)
{
    (void)in_sizes; (void)n_in; (void)out_size; (void)ws_size;
    const int*   idx    = (const int*)d_in[0];
    const float* lookup = (const float*)d_in[1];
    const float* wxf    = (const float*)d_in[2];
    const float* whf    = (const float*)d_in[3];
    const float* wxb    = (const float*)d_in[4];
    const float* whb    = (const float*)d_in[5];
    const float* wo     = (const float*)d_in[6];
    const float* hf0    = (const float*)d_in[7];
    const float* hb0    = (const float*)d_in[8];
    const float* bx     = (const float*)d_in[9];
    const float* bhf    = (const float*)d_in[10];
    const float* bhb    = (const float*)d_in[11];
    const float* bo     = (const float*)d_in[12];
    float* ws  = (float*)d_ws;
    float* out = (float*)d_out;

    hipLaunchKernelGGL(k1_embed_xw, dim3(16),  dim3(256), 0, stream,
                       idx, lookup, wxf, wxb, bx, bhf, bhb, ws);
    hipLaunchKernelGGL(k2_scan,     dim3(8),   dim3(64),  0, stream,
                       whf, whb, hf0, hb0, ws);
    hipLaunchKernelGGL(k3_sumexp,   dim3(512), dim3(256), 0, stream,
                       wo, bo, ws);
    hipLaunchKernelGGL(k4_write,    dim3(512), dim3(256), 0, stream,
                       wo, bo, ws, out);
}